// Round 4
// baseline (208.704 us; speedup 1.0000x reference)
//
// R23: 1024-thread (16-wave) restructure. R22 post-mortem: collision-free
// rotation gained ~0 over R21 -> L2-channel contention saturated. Remaining
// wall: ~38 GB/s/CU streaming with 2 waves/SIMD = concurrency starvation
// (rate ~ waves x inflight x 800B / 1000cy ~ 13B/cy matches). m56 hit 144
// GB/s/CU with 4x waves. So: 16 waves, all heavy phases repartitioned:
//  - lv2 matvec: 8 groups x 128 thr, 50-row slices (4 LDS + 12 VGPR + 34
//    streamed rows each); same cached bytes, 2x issue width.
//  - lv1 GEMM: j-split across two 400-thread halves (waves 0-6 / 8-14),
//    partials combined via LDS (aliased on s_part); halves global critical
//    path AND per-wave pT-broadcast ds_read count (~800 -> ~400).
//  - slice permutation ss=(gg+phase)&7, stream rotation mod 34, lv1 rotation
//    mod 200 kept (R21's -19% lever). Decode over 1024 thr. LDS ~133KB.
// Predict: dur 135 -> 85-100us if wave-MLP-limited (VALUBusy 35-45%,
// Occupancy ~45%, VGPR ~85-100); flat 125-140 falsifies -> next: sc0/L1-bypass
// asm loads. FETCH ~6.4MB, absmax <= 0.016 (sum reorder only).
#include <hip/hip_runtime.h>

#define kT 8
#define kG 120
#define kP 400
#define kObj 45
#define kS 10
#define kHid 200
#define NG 8          // matvec groups (slices)
#define SL 50         // rows per slice
#define NLr 4         // LDS-cached rows per slice
#define NVr 12        // VGPR-cached rows per slice
#define NSr (SL - NLr - NVr)   // 34 streamed rows per slice

__device__ __constant__ int c_gmap[40] = {
    0,1,2,3,4,5,6,7,8,9,
    30,31,32,33,34,35,36,37,38,39,
    60,61,62,63,64,65,66,67,
    84,85,86,87,88,89,
    102,103,104,105,106,107};

__device__ __constant__ float c_freq[5] = {0.01f, 0.7f, 0.91f, 0.97f, 0.99f};

__device__ __forceinline__ float leaky_clamp(float x) {
    x = fminf(fmaxf(x, -1.0f), 1.0f);
    return x > 0.0f ? x : 0.01f * x;
}

__global__ __launch_bounds__(1024, 1) void tem_kernel(
    const float* __restrict__ g_seq, const int* __restrict__ x_idx,
    const float* __restrict__ W_comp, const float* __restrict__ W_repeat,
    const float* __restrict__ W_tile, const float* __restrict__ W_tile0,
    const float* __restrict__ w_x, const float* __restrict__ b_x,
    const float* __restrict__ W1, const float* __restrict__ b1,
    const float* __restrict__ W2, const float* __restrict__ b2,
    const float* __restrict__ W_lv1, const float* __restrict__ b_lv1,
    const float* __restrict__ W_lv2, const float* __restrict__ b_lv2,
    float* __restrict__ out)
{
    const int b   = blockIdx.x;
    const int tid = threadIdx.x;
    const int dim = tid;
    const bool hasD = (tid < kP);
    const int wid  = tid >> 6;
    const int lane = tid & 63;
    const int gg  = tid >> 7;            // 0..7 matvec group
    const int r   = tid & 127;           // 0..127
    const bool mact = (r < 100);

    // per-co-XCD-block phase (co-XCD blocks: bid = x, x+8, x+16, ...)
    const int phase = blockIdx.x >> 3;               // 0..31
    const int ss  = (gg + phase) & 7;                // slice permutation
    const int sb  = ss * SL;                         // slice base row
    const int so  = phase % NSr;                     // stream rotation
    const int joff = (phase * 13) % 200;             // lv1 rotation per half

    __shared__ __align__(16) float pT[kP][kT];
    __shared__ __align__(16) float hT[kP][kT];   // decode scratch after loop
    __shared__ __align__(16) float lvT[kP][kT];  // decode scratch after loop
    __shared__ __align__(16) float xfT[50][kT];
    __shared__ __align__(16) float gdT[40][kT];
    __shared__ __align__(16) float s_wc[NG][NLr][kP];  // 51.2KB W_lv2 cache
    __shared__ float s_h[kP];
    __shared__ float s_u[kT][kP];
    __shared__ float s_v[kT][kP];
    __shared__ __align__(16) float s_part[NG][kP];     // also lv1 partial buf
    __shared__ float s_red[2][kT][8];
    __shared__ int   s_idx[kT];

    const float blv1 = hasD ? b_lv1[dim] : 0.0f;
    const float blv2 = hasD ? b_lv2[dim] : 0.0f;
    const float wx   = w_x[0];

    // ================= prologue =================
    if (tid < kT) s_idx[tid] = x_idx[b * kT + tid];
    __syncthreads();

    // LDS cache fill: W_lv2 rows sb..sb+NLr-1 of this slice
    if (mact) {
        #pragma unroll
        for (int k = 0; k < NLr; ++k)
            ((float4*)&s_wc[gg][k][0])[r] =
                ((const float4*)(W_lv2 + (sb + k) * kP))[r];
    }

    if (tid < 40) {
        int gi = c_gmap[tid];
        #pragma unroll
        for (int t = 0; t < kT; ++t)
            gdT[tid][t] = g_seq[(b * kT + t) * kG + gi];
    } else if (tid >= 64 && tid < 114) {
        int rr = tid - 64, d = rr % 10;
        float f = c_freq[rr / 10];
        float xf = 0.0f;
        #pragma unroll
        for (int t = 0; t < kT; ++t) {
            float xc = W_comp[s_idx[t] * kS + d];
            xf = (1.0f - f) * xf + f * xc;
            xfT[rr][t] = xf;
        }
    }
    __syncthreads();

    // projections for all 8 t: g_exp, x_exp -> p_inf, h_init
    if (hasD) {
        float ge[kT], xe[kT];
        #pragma unroll
        for (int t = 0; t < kT; ++t) { ge[t] = 0.0f; xe[t] = 0.0f; }
        for (int j = 0; j < 40; ++j) {
            float w = W_repeat[dim * 40 + j];
            float4 gA = *(const float4*)&gdT[j][0];
            float4 gB = *(const float4*)&gdT[j][4];
            ge[0] += w * gA.x; ge[1] += w * gA.y; ge[2] += w * gA.z; ge[3] += w * gA.w;
            ge[4] += w * gB.x; ge[5] += w * gB.y; ge[6] += w * gB.z; ge[7] += w * gB.w;
        }
        for (int j = 0; j < 50; ++j) {
            float w = W_tile[dim * 50 + j];
            float4 xA = *(const float4*)&xfT[j][0];
            float4 xB = *(const float4*)&xfT[j][4];
            xe[0] += w * xA.x; xe[1] += w * xA.y; xe[2] += w * xA.z; xe[3] += w * xA.w;
            xe[4] += w * xB.x; xe[5] += w * xB.y; xe[6] += w * xB.z; xe[7] += w * xB.w;
        }
        float4 pA, pB, hA, hB;
        pA.x = leaky_clamp(ge[0] * xe[0]); pA.y = leaky_clamp(ge[1] * xe[1]);
        pA.z = leaky_clamp(ge[2] * xe[2]); pA.w = leaky_clamp(ge[3] * xe[3]);
        pB.x = leaky_clamp(ge[4] * xe[4]); pB.y = leaky_clamp(ge[5] * xe[5]);
        pB.z = leaky_clamp(ge[6] * xe[6]); pB.w = leaky_clamp(ge[7] * xe[7]);
        hA.x = leaky_clamp(ge[0]); hA.y = leaky_clamp(ge[1]);
        hA.z = leaky_clamp(ge[2]); hA.w = leaky_clamp(ge[3]);
        hB.x = leaky_clamp(ge[4]); hB.y = leaky_clamp(ge[5]);
        hB.z = leaky_clamp(ge[6]); hB.w = leaky_clamp(ge[7]);
        *(float4*)&pT[dim][0] = pA; *(float4*)&pT[dim][4] = pB;
        *(float4*)&hT[dim][0] = hA; *(float4*)&hT[dim][4] = hB;
    }
    __syncthreads();

    // lv1 GEMM for all 8 t, j-SPLIT across two 400-thread halves:
    //   half A: threads 0..399   -> j in [0,200)
    //   half B: threads 512..911 -> j in [200,400)
    {
        const bool lvA = hasD;
        const bool lvB = (tid >= 512 && tid < 912);
        const int  ldim = lvA ? tid : (tid - 512);
        float acc[kT];
        #pragma unroll
        for (int t = 0; t < kT; ++t) acc[t] = 0.0f;
        if (lvA || lvB) {
            const int jbase = lvA ? 0 : 200;
            #pragma unroll 4
            for (int jj = joff; jj < 200; ++jj) {
                int j = jbase + jj;
                float w = W_lv1[j * kP + ldim];
                float4 pA = *(const float4*)&pT[j][0];
                float4 pB = *(const float4*)&pT[j][4];
                acc[0] += w * pA.x; acc[1] += w * pA.y; acc[2] += w * pA.z; acc[3] += w * pA.w;
                acc[4] += w * pB.x; acc[5] += w * pB.y; acc[6] += w * pB.z; acc[7] += w * pB.w;
            }
            #pragma unroll 4
            for (int jj = 0; jj < joff; ++jj) {
                int j = jbase + jj;
                float w = W_lv1[j * kP + ldim];
                float4 pA = *(const float4*)&pT[j][0];
                float4 pB = *(const float4*)&pT[j][4];
                acc[0] += w * pA.x; acc[1] += w * pA.y; acc[2] += w * pA.z; acc[3] += w * pA.w;
                acc[4] += w * pB.x; acc[5] += w * pB.y; acc[6] += w * pB.z; acc[7] += w * pB.w;
            }
        }
        float* lv1b = &s_part[0][0];   // alias: s_part unused until t-loop
        if (lvB) {
            ((float4*)lv1b)[ldim * 2 + 0] = make_float4(acc[0], acc[1], acc[2], acc[3]);
            ((float4*)lv1b)[ldim * 2 + 1] = make_float4(acc[4], acc[5], acc[6], acc[7]);
        }
        __syncthreads();
        if (hasD) {
            float4 bA = ((float4*)lv1b)[dim * 2 + 0];
            float4 bB = ((float4*)lv1b)[dim * 2 + 1];
            *(float4*)&lvT[dim][0] =
                make_float4(acc[0] + bA.x, acc[1] + bA.y, acc[2] + bA.z, acc[3] + bA.w);
            *(float4*)&lvT[dim][4] =
                make_float4(acc[4] + bB.x, acc[5] + bB.y, acc[6] + bB.z, acc[7] + bB.w);
        }
    }

    // VGPR cache fill: rows sb+NLr .. sb+NLr+NVr-1 of this slice
    float4 wreg[NVr];
    if (mact) {
        #pragma unroll
        for (int k = 0; k < NVr; ++k)
            wreg[k] = ((const float4*)(W_lv2 + (sb + NLr + k) * kP))[r];
    }

    // ================= recurrent steps =================
    int par = 0;
    for (int t = 0; t < kT; ++t) {
        // ---- attractor ----
        float h = hasD ? hT[dim][t] : 0.0f;
        if (t == 0) {
            #pragma unroll
            for (int it = 0; it < 5; ++it) h = leaky_clamp(0.8f * h);
        } else {
            for (int it = 0; it < 5; ++it) {
                if (tid < 512) {
                    for (int s = 0; s < t; ++s) {
                        float p = hasD ? s_v[s][dim] * h : 0.0f;
                        #pragma unroll
                        for (int off = 32; off; off >>= 1) p += __shfl_down(p, off, 64);
                        if (lane == 0) s_red[par][s][wid] = p;
                    }
                }
                __syncthreads();
                if (hasD) {
                    float mh = 0.0f;
                    float c = 0.5f;
                    for (int s = t - 1; s >= 0; --s) {
                        float d = 0.0f;
                        #pragma unroll
                        for (int w = 0; w < 8; ++w) d += s_red[par][s][w];
                        mh += c * d * s_u[s][dim];
                        c *= 0.9999f;
                    }
                    h = leaky_clamp(0.8f * h + mh);
                }
                par ^= 1;
            }
        }
        if (hasD) s_h[dim] = h;
        __syncthreads();

        // ---- lv2 matvec: 8 slices, LDS + VGPR + streamed (rotated) ----
        if (mact) {
            float4 a0{0,0,0,0}, a1{0,0,0,0};
            // LDS-cached rows sb..sb+3
            #pragma unroll
            for (int k = 0; k < NLr; k += 2) {
                float4 w0 = ((const float4*)&s_wc[gg][k+0][0])[r];
                float4 w1v = ((const float4*)&s_wc[gg][k+1][0])[r];
                float v0 = s_h[sb+k+0], v1 = s_h[sb+k+1];
                a0.x += w0.x * v0; a0.y += w0.y * v0; a0.z += w0.z * v0; a0.w += w0.w * v0;
                a1.x += w1v.x * v1; a1.y += w1v.y * v1; a1.z += w1v.z * v1; a1.w += w1v.w * v1;
            }
            // VGPR-cached rows sb+4..sb+15
            #pragma unroll
            for (int k = 0; k < NVr; k += 2) {
                float v0 = s_h[sb+NLr+k+0], v1 = s_h[sb+NLr+k+1];
                a0.x += wreg[k].x * v0; a0.y += wreg[k].y * v0; a0.z += wreg[k].z * v0; a0.w += wreg[k].w * v0;
                a1.x += wreg[k+1].x * v1; a1.y += wreg[k+1].y * v1; a1.z += wreg[k+1].z * v1; a1.w += wreg[k+1].w * v1;
            }
            // streamed rows sb+16..sb+49, rotated start (32 phases mod 34)
            const float* Wbase = W_lv2 + (sb + NLr + NVr) * kP;
            #pragma unroll 4
            for (int jj = 0; jj < NSr; jj += 2) {
                int i0 = jj + so;     i0 -= (i0 >= NSr) ? NSr : 0;
                int i1 = jj + 1 + so; i1 -= (i1 >= NSr) ? NSr : 0;
                float4 w0 = ((const float4*)(Wbase + i0 * kP))[r];
                float4 w1v = ((const float4*)(Wbase + i1 * kP))[r];
                float v0 = s_h[sb + NLr + NVr + i0];
                float v1 = s_h[sb + NLr + NVr + i1];
                a0.x += w0.x * v0; a0.y += w0.y * v0; a0.z += w0.z * v0; a0.w += w0.w * v0;
                a1.x += w1v.x * v1; a1.y += w1v.y * v1; a1.z += w1v.z * v1; a1.w += w1v.w * v1;
            }
            float4 tot;
            tot.x = a0.x + a1.x; tot.y = a0.y + a1.y;
            tot.z = a0.z + a1.z; tot.w = a0.w + a1.w;
            ((float4*)&s_part[gg][0])[r] = tot;
        }
        __syncthreads();

        // ---- fusion (no trailing barrier: next cross-thread access is
        //      behind the attractor/s_h barriers) ----
        if (hasD) {
            float lv2raw = ((s_part[0][dim] + s_part[1][dim])
                          + (s_part[2][dim] + s_part[3][dim]))
                         + ((s_part[4][dim] + s_part[5][dim])
                          + (s_part[6][dim] + s_part[7][dim])) + blv2;
            float lv1raw = lvT[dim][t] + blv1;
            float l1 = -2.0f + 6.0f * tanhf(lv1raw * (1.0f / 6.0f));
            float l2 = -2.0f + 6.0f * tanhf(lv2raw * (1.0f / 6.0f));
            float i1v = expf(-l1), i2v = expf(-l2);
            float pinf = pT[dim][t];
            float p = (pinf * i1v + h * i2v) / (i1v + i2v);
            s_u[t][dim] = p - h;
            s_v[t][dim] = p + h;
        }
    }
    __syncthreads();   // publish all s_u/s_v for decode

    // ================= deferred decode, all 8 t at once =================
    // p_t[j] == 0.5*(s_u[t][j] + s_v[t][j]); decode needs only j<100.
    float* dsc  = &hT[0][0];    // 3200 floats scratch
    float* dhid = &lvT[0][0];   // 3200 floats scratch

    // A: xs partials — (t,d,k): k-th twelfth of j in [0,100)
    if (tid < 960) {
        int t = tid / 120, rem = tid % 120;
        int d = rem / 12, k = rem % 12;
        int jlo = (k * 100) / 12, jhi = ((k + 1) * 100) / 12;
        float acc = 0.0f;
        for (int j = jlo; j < jhi; ++j) {
            float pj = 0.5f * (s_u[t][j] + s_v[t][j]);
            acc += pj * W_tile0[j * kS + d];
        }
        dsc[(t * 10 + d) * 12 + k] = acc;
    }
    __syncthreads();
    // B: xs finalize
    if (tid < 80) {
        int t = tid / 10, d = tid % 10;
        float acc = 0.0f;
        #pragma unroll
        for (int k = 0; k < 12; ++k) acc += dsc[(t * 10 + d) * 12 + k];
        dsc[1200 + t * 10 + d] = wx * acc + b_x[d];
    }
    __syncthreads();
    // C: hidden layer, 1600 outputs over 1024 threads
    for (int idx = tid; idx < kT * kHid; idx += 1024) {
        int t = idx / kHid, hh = idx - t * kHid;
        float acc = b1[hh];
        #pragma unroll
        for (int d = 0; d < kS; ++d)
            acc += dsc[1200 + t * 10 + d] * W1[d * kHid + hh];
        dhid[t * kHid + hh] = acc > 0.0f ? acc : (expf(acc) - 1.0f);
    }
    __syncthreads();
    // D: logit partials, (t,half,o): half-sums over 100 hid each
    if (tid < 720) {
        int t = tid / 90, rem = tid - t * 90;
        int half = rem / kObj, o = rem - half * kObj;
        int h0 = half * 100;
        float acc = 0.0f;
        for (int hh = h0; hh < h0 + 100; ++hh)
            acc += dhid[t * kHid + hh] * W2[hh * kObj + o];
        dsc[2000 + tid] = acc;
    }
    __syncthreads();
    // E: combine + write out
    if (tid < 360) {
        int t = tid / kObj, o = tid - t * kObj;
        out[(b * kT + t) * kObj + o] =
            b2[o] + dsc[2000 + t * 90 + o] + dsc[2000 + t * 90 + kObj + o];
    }
}

extern "C" void kernel_launch(void* const* d_in, const int* in_sizes, int n_in,
                              void* d_out, int out_size, void* d_ws, size_t ws_size,
                              hipStream_t stream) {
    const float* g_seq   = (const float*)d_in[0];
    const int*   x_idx   = (const int*)d_in[1];
    const float* W_comp  = (const float*)d_in[2];
    const float* W_repeat= (const float*)d_in[3];
    const float* W_tile  = (const float*)d_in[4];
    const float* W_tile0 = (const float*)d_in[5];
    const float* w_x     = (const float*)d_in[6];
    const float* b_x     = (const float*)d_in[7];
    const float* W1      = (const float*)d_in[8];
    const float* b1      = (const float*)d_in[9];
    const float* W2      = (const float*)d_in[10];
    const float* b2      = (const float*)d_in[11];
    const float* W_lv1   = (const float*)d_in[12];
    const float* b_lv1   = (const float*)d_in[13];
    const float* W_lv2   = (const float*)d_in[14];
    const float* b_lv2   = (const float*)d_in[15];
    float* out = (float*)d_out;

    const int Bn = in_sizes[0] / (kT * kG);
    tem_kernel<<<dim3(Bn), dim3(1024), 0, stream>>>(
        g_seq, x_idx, W_comp, W_repeat, W_tile, W_tile0, w_x, b_x,
        W1, b1, W2, b2, W_lv1, b_lv1, W_lv2, b_lv2, out);
}